// Round 10
// baseline (6293.557 us; speedup 1.0000x reference)
//
#include <hip/hip_runtime.h>
#include <math.h>

// Problem constants
#define D_MODEL 1024
#define N_WIN   240
#define TOK     256
#define NH      16
#define DH      64
#define CHUNK   8
#define NCHUNK  30
#define WIN     ((size_t)TOK * D_MODEL)

typedef unsigned short ushort_t;
typedef unsigned long long ull_t;
typedef __attribute__((ext_vector_type(8))) short short8;
typedef __attribute__((ext_vector_type(4))) float floatx4;

__device__ __forceinline__ ushort_t f2bf(float f) {   // RNE
    unsigned u = __float_as_uint(f);
    unsigned lsb = (u >> 16) & 1u;
    u += 0x7fffu + lsb;
    return (ushort_t)(u >> 16);
}

// ---------------------------------------------------------------------------
// Coherence: write-through (sc1) -> IC for every cross-WG consumed buffer;
// readers' L2s invalidated at launch start; 8-slot rotation guarantees no
// read-before-write within a launch. Qchunk double-buffered across launches.
//
// Round-22 = round-21 + ONE change (T14 on the V-peer gather): after the
// head barrier, V-peer slices are only ISSUED into registers; their LDS
// write happens after QK^T+softmax (latency hidden under ~2 us of compute),
// with a sync before PV. Bit-identical values/addresses (absmax canary
// 6.430412e-13). Everything else unchanged from round-21.
// ---------------------------------------------------------------------------
__device__ __forceinline__ void st2_wt(ushort_t* p, ushort_t v) {
    unsigned vv = v;
    asm volatile("global_store_short %0, %1, off sc1"
                 :: "v"(p), "v"(vv) : "memory");
}
__device__ __forceinline__ void st8_wt(ushort_t* p, ushort4 v) {
    ull_t dv = (ull_t)((unsigned)v.x | ((unsigned)v.y << 16))
             | ((ull_t)((unsigned)v.z | ((unsigned)v.w << 16)) << 32);
    asm volatile("global_store_dwordx2 %0, %1, off sc1"
                 :: "v"(p), "v"(dv) : "memory");
}
__device__ __forceinline__ void rel_drain() {
    asm volatile("s_waitcnt vmcnt(0)" ::: "memory");
}

// async global->LDS, 16B per lane (GEMM staging)
#define GLDS(g, l) __builtin_amdgcn_global_load_lds( \
    (const __attribute__((address_space(1))) unsigned int*)(g), \
    (__attribute__((address_space(3))) unsigned int*)(l), 16, 0, 0)

// ---------------------------------------------------------------------------
// Helper barrier among the 192 phase-1 helper WGs (24 subs x 8 arrivals).
// ---------------------------------------------------------------------------
__device__ __forceinline__ void help_bar(unsigned* base, int g, unsigned s)
{
    rel_drain();
    __syncthreads();
    if (threadIdx.x == 0) {
        unsigned old = __hip_atomic_fetch_add(base + 1024 + g * 32, 1u,
                __ATOMIC_RELAXED, __HIP_MEMORY_SCOPE_AGENT);
        if (old == 8u * s - 1u) {
            unsigned r = __hip_atomic_fetch_add(base + 1800, 1u,
                    __ATOMIC_RELAXED, __HIP_MEMORY_SCOPE_AGENT);
            if (r == 24u * s - 1u)
                __hip_atomic_store(base + 1832, s, __ATOMIC_RELAXED,
                                   __HIP_MEMORY_SCOPE_AGENT);
        }
        while (__hip_atomic_load(base + 1832, __ATOMIC_RELAXED,
                                 __HIP_MEMORY_SCOPE_AGENT) < s)
            __builtin_amdgcn_s_sleep(1);
    }
    __syncthreads();
}

// ---------------------------------------------------------------------------
// fp32 -> bf16 cast
// ---------------------------------------------------------------------------
__global__ __launch_bounds__(256) void cast_bf_k(
    const float* __restrict__ s, ushort_t* __restrict__ d, int n)
{
    int i = (blockIdx.x * 256 + threadIdx.x) * 4;
    if (i >= n) return;
    float4 v = *(const float4*)(s + i);
    ushort4 o;
    o.x = f2bf(v.x); o.y = f2bf(v.y); o.z = f2bf(v.z); o.w = f2bf(v.w);
    *(ushort4*)(d + i) = o;
}

// 64x64-tile bf16 transpose: dst[c][r] = src[r][c], both 1024x1024
__global__ __launch_bounds__(256) void transpose_k(
    const ushort_t* __restrict__ src, ushort_t* __restrict__ dst)
{
    __shared__ ushort_t t[64][65];
    const int bx = blockIdx.x * 64, by = blockIdx.y * 64;
    const int c = threadIdx.x & 63, r0 = threadIdx.x >> 6;
#pragma unroll
    for (int k = 0; k < 16; ++k) {
        int r = r0 + k * 4;
        t[r][c] = src[(size_t)(by + r) * 1024 + bx + c];
    }
    __syncthreads();
#pragma unroll
    for (int k = 0; k < 16; ++k) {
        int r = r0 + k * 4;
        dst[(size_t)(bx + r) * 1024 + by + c] = t[c][r];
    }
}

// bc[n] = b_in2[1024+n] + dot(w_in2 row (1024+n), b_out2), fp32, n in [0,2048)
__global__ __launch_bounds__(256) void bc_k(
    const float* __restrict__ w_in2, const float* __restrict__ b_in2,
    const float* __restrict__ b_out2, float* __restrict__ bc)
{
    int n = blockIdx.x * 256 + threadIdx.x;
    const float* row = w_in2 + (size_t)(1024 + n) * 1024;
    float s = b_in2[1024 + n];
    for (int j = 0; j < 1024; j += 4) {
        float4 w = *(const float4*)(row + j);
        float4 b = *(const float4*)(b_out2 + j);
        s += w.x * b.x + w.y * b.y + w.z * b.z + w.w * b.w;
    }
    bc[n] = s;
}

// ---------------------------------------------------------------------------
// bf16 MFMA GEMM core (m97 structure), 128x128 tile, BK=32.
// ---------------------------------------------------------------------------
template<bool GATHER, bool WT>
__device__ __forceinline__ void gemm_core(
    ushort_t* As, ushort_t* Bs,
    const ushort_t* __restrict__ A, int lda, int w0,
    const ushort_t* __restrict__ W, const float* __restrict__ bias,
    ushort_t* __restrict__ Cb, float* __restrict__ Cf, int ldc,
    int K, int m0, int n0, int co, int relu)
{
    const int tid = threadIdx.x;
    const int wave = tid >> 6, lane = tid & 63;
    const int wm = wave & 1, wn = wave >> 1;

    int r0 = m0 + (tid >> 2), r1 = r0 + 64;
    if (GATHER) {
        r0 = (w0 + (r0 >> 8)) * 16 + (r0 & 255);
        r1 = (w0 + (r1 >> 8)) * 16 + (r1 & 255);
    }
    const int kcol = (tid & 3) * 8;
    const ushort_t* gA0 = A + (size_t)r0 * lda + kcol;
    const ushort_t* gA1 = A + (size_t)r1 * lda + kcol;
    const ushort_t* pW  = W + (size_t)n0 * K;
    const ushort_t* gB0 = pW + (size_t)(tid >> 2) * K + kcol;
    const ushort_t* gB1 = gB0 + (size_t)64 * K;
    ushort_t* lA = As + wave * 512;
    ushort_t* lB = Bs + wave * 512;

    floatx4 acc[4][4];
#pragma unroll
    for (int i = 0; i < 4; ++i)
#pragma unroll
        for (int j = 0; j < 4; ++j) acc[i][j] = (floatx4){0.f, 0.f, 0.f, 0.f};

    const int fr = lane & 15, fk = (lane >> 4) * 8;
    const int arow = (wm * 64 + fr) * 32 + fk;
    const int brow = (wn * 64 + fr) * 32 + fk;

    for (int k0 = 0; k0 < K; k0 += 32) {
        GLDS(gA0 + k0, lA);
        GLDS(gA1 + k0, lA + 2048);
        GLDS(gB0 + k0, lB);
        GLDS(gB1 + k0, lB + 2048);
        __syncthreads();
        short8 a[4], b[4];
#pragma unroll
        for (int mi = 0; mi < 4; ++mi) a[mi] = *(const short8*)&As[arow + mi * 512];
#pragma unroll
        for (int ni = 0; ni < 4; ++ni) b[ni] = *(const short8*)&Bs[brow + ni * 512];
#pragma unroll
        for (int mi = 0; mi < 4; ++mi)
#pragma unroll
            for (int ni = 0; ni < 4; ++ni)
                acc[mi][ni] = __builtin_amdgcn_mfma_f32_16x16x32_bf16(
                    a[mi], b[ni], acc[mi][ni], 0, 0, 0);
        __syncthreads();
    }

    const int crq = (lane >> 4) * 4;
    const int ccol = lane & 15;
#pragma unroll
    for (int mi = 0; mi < 4; ++mi) {
#pragma unroll
        for (int ni = 0; ni < 4; ++ni) {
            int lc = wn * 64 + ni * 16 + ccol;
            float bz = bias[n0 + lc];
#pragma unroll
            for (int rg = 0; rg < 4; ++rg) {
                int row = m0 + wm * 64 + mi * 16 + crq + rg;
                float v = acc[mi][ni][rg] + bz;
                if (relu) v = fmaxf(v, 0.f);
                size_t off = (size_t)row * ldc + co + lc;
                if (Cb) {
                    if (WT) st2_wt(Cb + off, f2bf(v));
                    else    Cb[off] = f2bf(v);
                }
                if (Cf) Cf[off] = v;
            }
        }
    }
}

__global__ __launch_bounds__(256) void gemm_bf_k(
    const ushort_t* __restrict__ A, int lda,
    const ushort_t* __restrict__ W, const float* __restrict__ bias,
    ushort_t* __restrict__ Cb, float* __restrict__ Cf, int ldc,
    int K, int relu)
{
    __shared__ ushort_t As[128 * 32];
    __shared__ ushort_t Bs[128 * 32];
    gemm_core<false, false>(As, Bs, A, lda, 0, W, bias, Cb, Cf, ldc, K,
                            blockIdx.y * 128, blockIdx.x * 128, blockIdx.x * 128, relu);
}

__global__ __launch_bounds__(256) void gemm_qkv_k(
    const ushort_t* __restrict__ path_bf, const ushort_t* __restrict__ W,
    const float* __restrict__ bias, ushort_t* __restrict__ Cb, int w0)
{
    __shared__ ushort_t As[128 * 32];
    __shared__ ushort_t Bs[128 * 32];
    gemm_core<true, false>(As, Bs, path_bf, 1024, w0, W, bias, Cb, nullptr, 3072, 1024,
                           blockIdx.y * 128, blockIdx.x * 128, blockIdx.x * 128, 0);
}

// ---------------------------------------------------------------------------
// Phase-1 MFMA attention body (O stores write-through for fused consumers).
// ---------------------------------------------------------------------------
#define PLD 260
#define VLD 132

struct AttnShared {
    ushort_t P[64 * PLD];
    ushort_t VT[64 * VLD];
    float    l[64];
};

__device__ void attn_body(AttnShared& sh,
    const ushort_t* __restrict__ qkv, ushort_t* __restrict__ ao,
    int rs, int h, int b)
{
    const ushort_t* base = qkv + (size_t)b * TOK * 3072;
    const ushort_t* Q = base;
    const ushort_t* K = base + 1024;
    const ushort_t* V = base + 2048;
    ushort_t* O = ao + (size_t)b * TOK * 1024;
    const int ldq = 3072, ldkv = 3072, ldo = 1024;
    const int tid = threadIdx.x;
    const int wave = tid >> 6, lane = tid & 63;
    const int fr = lane & 15, q = lane >> 4, fk = q * 8;
    const ushort_t* Qh = Q + (size_t)(rs * 64) * ldq + h * 64;
    const ushort_t* Kh = K + h * 64;
    const ushort_t* Vh = V + h * 64;
    const int m0 = wave * 16;

    floatx4 s[16];
#pragma unroll
    for (int nt = 0; nt < 16; ++nt) s[nt] = (floatx4){0.f, 0.f, 0.f, 0.f};
#pragma unroll
    for (int kc = 0; kc < 64; kc += 32) {
        short8 a = *(const short8*)(Qh + (size_t)(m0 + fr) * ldq + kc + fk);
#pragma unroll
        for (int nt = 0; nt < 16; ++nt) {
            short8 b2 = *(const short8*)(Kh + (size_t)(nt * 16 + fr) * ldkv + kc + fk);
            s[nt] = __builtin_amdgcn_mfma_f32_16x16x32_bf16(a, b2, s[nt], 0, 0, 0);
        }
    }

    float rmax[4] = {-INFINITY, -INFINITY, -INFINITY, -INFINITY};
#pragma unroll
    for (int nt = 0; nt < 16; ++nt)
#pragma unroll
        for (int rg = 0; rg < 4; ++rg) rmax[rg] = fmaxf(rmax[rg], s[nt][rg]);
#pragma unroll
    for (int d = 1; d < 16; d <<= 1)
#pragma unroll
        for (int rg = 0; rg < 4; ++rg)
            rmax[rg] = fmaxf(rmax[rg], __shfl_xor(rmax[rg], d));

    float rsum[4] = {0.f, 0.f, 0.f, 0.f};
#pragma unroll
    for (int nt = 0; nt < 16; ++nt) {
#pragma unroll
        for (int rg = 0; rg < 4; ++rg) {
            float p = __expf((s[nt][rg] - rmax[rg]) * 0.125f);
            rsum[rg] += p;
            sh.P[(m0 + q * 4 + rg) * PLD + nt * 16 + fr] = f2bf(p);
        }
    }
#pragma unroll
    for (int d = 1; d < 16; d <<= 1)
#pragma unroll
        for (int rg = 0; rg < 4; ++rg) rsum[rg] += __shfl_xor(rsum[rg], d);
    if (fr == 0) {
#pragma unroll
        for (int rg = 0; rg < 4; ++rg) sh.l[m0 + q * 4 + rg] = rsum[rg];
    }
    __syncthreads();

    floatx4 o[4];
#pragma unroll
    for (int i = 0; i < 4; ++i) o[i] = (floatx4){0.f, 0.f, 0.f, 0.f};

#pragma unroll
    for (int half = 0; half < 2; ++half) {
        {
            int r = tid & 127, cp = tid >> 7;
            const ushort_t* vrow = Vh + (size_t)(half * 128 + r) * ldkv + cp * 32;
#pragma unroll
            for (int c = 0; c < 4; ++c) {
                uint4 pk = *(const uint4*)(vrow + c * 8);
                int d0 = cp * 32 + c * 8;
                sh.VT[(d0 + 0) * VLD + r] = (ushort_t)(pk.x & 0xffff);
                sh.VT[(d0 + 1) * VLD + r] = (ushort_t)(pk.x >> 16);
                sh.VT[(d0 + 2) * VLD + r] = (ushort_t)(pk.y & 0xffff);
                sh.VT[(d0 + 3) * VLD + r] = (ushort_t)(pk.y >> 16);
                sh.VT[(d0 + 4) * VLD + r] = (ushort_t)(pk.z & 0xffff);
                sh.VT[(d0 + 5) * VLD + r] = (ushort_t)(pk.z >> 16);
                sh.VT[(d0 + 6) * VLD + r] = (ushort_t)(pk.w & 0xffff);
                sh.VT[(d0 + 7) * VLD + r] = (ushort_t)(pk.w >> 16);
            }
        }
        __syncthreads();
#pragma unroll
        for (int ks = 0; ks < 4; ++ks) {
            short8 a = *(const short8*)&sh.P[(m0 + fr) * PLD + half * 128 + ks * 32 + fk];
#pragma unroll
            for (int nt2 = 0; nt2 < 4; ++nt2) {
                short8 b2 = *(const short8*)&sh.VT[(nt2 * 16 + fr) * VLD + ks * 32 + fk];
                o[nt2] = __builtin_amdgcn_mfma_f32_16x16x32_bf16(a, b2, o[nt2], 0, 0, 0);
            }
        }
        __syncthreads();
    }

    float linv[4];
#pragma unroll
    for (int rg = 0; rg < 4; ++rg) linv[rg] = 1.f / sh.l[m0 + q * 4 + rg];
#pragma unroll
    for (int nt2 = 0; nt2 < 4; ++nt2)
#pragma unroll
        for (int rg = 0; rg < 4; ++rg) {
            int row = rs * 64 + m0 + q * 4 + rg;
            st2_wt(O + (size_t)row * ldo + h * 64 + nt2 * 16 + fr,
                   f2bf(o[nt2][rg] * linv[rg]));
        }
    __syncthreads();   // protect sh.l/sh.P across back-to-back calls
}

__global__ __launch_bounds__(256) void attn_mfma_k(
    const ushort_t* __restrict__ qkv, ushort_t* __restrict__ ao)
{
    __shared__ AttnShared sh;
    attn_body(sh, qkv, ao, blockIdx.x, blockIdx.y, blockIdx.z);
}

// ===========================================================================
// Scan body (round-22): BK=128 single-barrier KV loop (A/W 3-deep),
// per-rs 16-WG grid barrier, arrive/wait splits; V-peer gather issued into
// registers before QK and LDS-written after softmax (latency hidden).
// ===========================================================================
#define KLD 76    // K stride (152 B) — conflict-free QK reads
#define TLD 264   // Vt / P stride (528 B)

struct ScanSmem {
    union {
        struct { ushort_t Ab[3][8192]; ushort_t Wb[3][16384]; } st;   // 144 KB
        struct { ushort_t Kl[256 * KLD]; ushort_t Vt[64 * TLD];
                 ushort_t P[64 * TLD]; } at;                          // 104 KB
    };
};

__device__ __forceinline__ void stage_A(
    const ushort_t* __restrict__ A64, int k0, ushort_t* __restrict__ Ad,
    int wave, int lane)
{
    // A sub-chunk: 64 rows x 64 cols (8 KB) = 2 GLDS per wave
#pragma unroll
    for (int t = 0; t < 2; ++t) {
        int j = wave * 128 + t * 64 + lane;        // 16B slot index
        int row = j >> 3;
        int blk = (j & 7) ^ (row & 7);             // inverse swizzle on source
        GLDS(A64 + (size_t)row * 1024 + k0 + blk * 8,
             Ad + wave * 1024 + t * 512);
    }
}

__device__ __forceinline__ void stage_W(
    const ushort_t* __restrict__ Wsel, int h, int k0,
    ushort_t* __restrict__ Wd, int wave, int lane)
{
    // W sub-chunk: 128 rows x 64 cols (16 KB) = 4 GLDS per wave
#pragma unroll
    for (int t = 0; t < 4; ++t) {
        int j = wave * 256 + t * 64 + lane;
        int r = j >> 3;
        int blk = (j & 7) ^ (r & 7);
        int n = ((r >> 6) << 10) + h * 64 + (r & 63);
        GLDS(Wsel + (size_t)n * 1024 + k0 + blk * 8,
             Wd + wave * 2048 + t * 512);
    }
}

__device__ void scan_body(
    ScanSmem& sm, int h, int rs,
    const ushort_t* __restrict__ Qchunk, int i0, int w0, int nsteps,
    const ushort_t* __restrict__ x0, ushort_t* __restrict__ AOb,
    ushort_t* __restrict__ KVx,
    const ushort_t* __restrict__ Wkv, const float* __restrict__ bkv,
    const ushort_t* __restrict__ Wc, const float* __restrict__ bc,
    unsigned* __restrict__ bar, unsigned s0)
{
    const int tid = threadIdx.x;
    const int wave = tid >> 6, lane = tid & 63;
    const int fr = lane & 15, q = lane >> 4, fk = q * 8;
    const int m0g = rs * 64 + wave * 16;

    // per-wave bias hoist: dims = (wave&1)*32 + nt*16 + fr;
    // waves 0,1 -> K section, waves 2,3 -> V section.
    const int dbofs = (wave < 2 ? 0 : 1024) + h * 64 + (wave & 1) * 32;
    float bK1[2], bC1[2];
#pragma unroll
    for (int nt = 0; nt < 2; ++nt) {
        bK1[nt] = bkv[dbofs + nt * 16 + fr];
        bC1[nt] = bc[dbofs + nt * 16 + fr];
    }

    ushort_t* Kl = sm.at.Kl;
    ushort_t* Vt = sm.at.Vt;
    ushort_t* P  = sm.at.P;

    short8 qf0, qf1;
    // first-step prologue: W chunk 0 (both subs) + Q + A chunk 0 (both subs)
    {
        const int i = i0;
        const ushort_t* Wsel0 = (i == 1) ? Wkv : Wc;
        stage_W(Wsel0, h, 0,  sm.st.Wb[0], wave, lane);
        stage_W(Wsel0, h, 64, sm.st.Wb[0] + 8192, wave, lane);
        const ushort_t* Qrow = Qchunk + (size_t)(i - w0) * WIN
            + (size_t)(m0g + fr) * 1024 + h * 64;
        qf0 = *(const short8*)(Qrow);
        qf1 = *(const short8*)(Qrow + 32);
        const ushort_t* Asrc0 = (i == 1) ? x0
            : AOb + (size_t)((i - 1) & 7) * WIN;
        stage_A(Asrc0 + (size_t)rs * 64 * 1024, 0,  sm.st.Ab[0], wave, lane);
        stage_A(Asrc0 + (size_t)rs * 64 * 1024, 64, sm.st.Ab[0] + 4096, wave, lane);
    }

    unsigned s = s0;
    for (int t0 = 0; t0 < nsteps; ++t0, ++s) {
        const int i = i0 + t0;
        const ushort_t* Asrc = (i == 1) ? x0
            : AOb + (size_t)((i - 1) & 7) * WIN;
        const ushort_t* Wsel = (i == 1) ? Wkv : Wc;
        const ushort_t* A64 = Asrc + (size_t)rs * 64 * 1024;
        ushort_t* KVs = KVx + (size_t)(i & 7) * (NH * 32768) + h * 32768;

        // ---------- KV build: keys [rs*64,+64) x 128 dims, BK=128 ----------
        floatx4 acc[4][2];
#pragma unroll
        for (int mt = 0; mt < 4; ++mt)
#pragma unroll
            for (int nt = 0; nt < 2; ++nt)
                acc[mt][nt] = (floatx4){0.f, 0.f, 0.f, 0.f};

        // Single-barrier pipeline, 3-deep both: buf[(t+1)%3] written at iter
        // t, last read at iter t-2 — all waves passed barrier t-1 first.
#pragma unroll 1
        for (int t = 0; t < 8; ++t) {
            if (t < 7) {
                stage_A(A64, (t + 1) * 128,      sm.st.Ab[(t + 1) % 3], wave, lane);
                stage_A(A64, (t + 1) * 128 + 64, sm.st.Ab[(t + 1) % 3] + 4096, wave, lane);
                stage_W(Wsel, h, (t + 1) * 128,      sm.st.Wb[(t + 1) % 3], wave, lane);
                stage_W(Wsel, h, (t + 1) * 128 + 64, sm.st.Wb[(t + 1) % 3] + 8192, wave, lane);
                asm volatile("s_waitcnt vmcnt(12)" ::: "memory");
            } else {
                asm volatile("s_waitcnt vmcnt(0)" ::: "memory");
            }
            __builtin_amdgcn_s_barrier();          // chunk t resident (all waves)
            const ushort_t* Ac  = sm.st.Ab[t % 3];
            const ushort_t* Wc_ = sm.st.Wb[t % 3];
#pragma unroll
            for (int sub = 0; sub < 2; ++sub) {
                const ushort_t* Acs = Ac  + sub * 4096;
                const ushort_t* Wcs = Wc_ + sub * 8192;
#pragma unroll
                for (int kh = 0; kh < 2; ++kh) {
                    const int pb = (((kh << 2) + q) ^ (fr & 7)) * 8;
                    short8 a[4];
#pragma unroll
                    for (int mt = 0; mt < 4; ++mt)
                        a[mt] = *(const short8*)&Acs[(mt * 16 + fr) * 64 + pb];
#pragma unroll
                    for (int nt = 0; nt < 2; ++nt) {
                        short8 b = *(const short8*)
                            &Wcs[(wave * 32 + nt * 16 + fr) * 64 + pb];
#pragma unroll
                        for (int mt = 0; mt < 4; ++mt)
                            acc[mt][nt] = __builtin_amdgcn_mfma_f32_16x16x32_bf16(
                                a[mt], b, acc[mt][nt], 0, 0, 0);
                    }
                }
            }
        }
        __builtin_amdgcn_s_barrier();              // all compute done before
                                                   // epilogue aliases staging
        // ---- exchange: write full K/V slice to global slot (for peers) ----
        ushort_t* Kx = KVs;                        // [key][64]
        ushort_t* Vx = KVs + 16384;                // [dim][256]
#pragma unroll
        for (int mt = 0; mt < 4; ++mt) {
#pragma unroll
            for (int nt = 0; nt < 2; ++nt) {
                const float bz = (i == 1) ? bK1[nt] : bC1[nt];
                const int d = (wave & 1) * 32 + nt * 16 + fr;
                if (wave < 2) {
#pragma unroll
                    for (int rg = 0; rg < 4; ++rg) {
                        const int key = rs * 64 + mt * 16 + q * 4 + rg;
                        st2_wt(Kx + key * 64 + d, f2bf(acc[mt][nt][rg] + bz));
                    }
                } else {
                    ushort4 pv;
                    pv.x = f2bf(acc[mt][nt][0] + bz);
                    pv.y = f2bf(acc[mt][nt][1] + bz);
                    pv.z = f2bf(acc[mt][nt][2] + bz);
                    pv.w = f2bf(acc[mt][nt][3] + bz);
                    st8_wt(Vx + d * 256 + rs * 64 + mt * 16 + q * 4, pv);
                }
            }
        }
        rel_drain();
        __syncthreads();
        if (tid == 0)                              // head arrive
            __hip_atomic_fetch_add(bar + 384 + h * 32, 1u,
                    __ATOMIC_RELAXED, __HIP_MEMORY_SCOPE_AGENT);

        // own-slice direct LDS write (bit-identical to the gather path)
#pragma unroll
        for (int mt = 0; mt < 4; ++mt) {
#pragma unroll
            for (int nt = 0; nt < 2; ++nt) {
                const float bz = (i == 1) ? bK1[nt] : bC1[nt];
                const int d = (wave & 1) * 32 + nt * 16 + fr;
                if (wave < 2) {
#pragma unroll
                    for (int rg = 0; rg < 4; ++rg) {
                        const int key = rs * 64 + mt * 16 + q * 4 + rg;
                        Kl[key * KLD + d] = f2bf(acc[mt][nt][rg] + bz);
                    }
                } else {
                    ushort4 pv;
                    pv.x = f2bf(acc[mt][nt][0] + bz);
                    pv.y = f2bf(acc[mt][nt][1] + bz);
                    pv.z = f2bf(acc[mt][nt][2] + bz);
                    pv.w = f2bf(acc[mt][nt][3] + bz);
                    *(ushort4*)&Vt[d * TLD + rs * 64 + mt * 16 + q * 4] = pv;
                }
            }
        }
        if (tid == 0) {                            // head wait
            while (__hip_atomic_load(bar + 384 + h * 32, __ATOMIC_RELAXED,
                                     __HIP_MEMORY_SCOPE_AGENT) < 4u * s)
                __builtin_amdgcn_s_sleep(1);
        }
        __syncthreads();

        // ---- K-peer gather into LDS; V-peer loads ISSUED into registers ----
        const int vd = tid >> 2, vq = tid & 3;
        uint4 vb4[8];
        {
            if (vq != rs) {                        // issue V loads (regs only)
                const ushort_t* vr = Vx + vd * 256 + vq * 64;
#pragma unroll
                for (int s8 = 0; s8 < 8; ++s8)
                    vb4[s8] = *(const uint4*)(vr + s8 * 8);
            }
            if (wave != rs) {                      // K: thread -> key row tid
                const ushort_t* kr = Kx + tid * 64;
                uint4 kb4[8];
#pragma unroll
                for (int s8 = 0; s8 < 8; ++s8)
                    kb4[s8] = *(const uint4*)(kr + s8 * 8);
                const int kp = (tid >> 4) & 3;     // seg rotation (bank spread)
#pragma unroll
                for (int s8 = 0; s8 < 8; ++s8) {
                    int ks = (s8 + kp) & 7;
                    *(uint4*)&Kl[tid * KLD + ks * 8] = kb4[ks];
                }
            }
        }
        __syncthreads();                           // Kl visible (V still in flight)

        // ---------- attention: wave w -> rows rs*64 + w*16 .. +16 ----------
        ushort_t* AOcur = AOb + (size_t)(i & 7) * WIN;
        {
            const int pl0 = wave * 16;              // local P row base
            floatx4 sc[16];
#pragma unroll
            for (int nt = 0; nt < 16; ++nt) sc[nt] = (floatx4){0.f, 0.f, 0.f, 0.f};
#pragma unroll
            for (int kc = 0; kc < 64; kc += 32) {
                short8 a = (kc == 0) ? qf0 : qf1;
#pragma unroll
                for (int nt = 0; nt < 16; ++nt) {
                    short8 b = *(const short8*)&Kl[(nt * 16 + fr) * KLD + kc + fk];
                    sc[nt] = __builtin_amdgcn_mfma_f32_16x16x32_bf16(
                        a, b, sc[nt], 0, 0, 0);
                }
            }
            float rmax[4] = {-INFINITY, -INFINITY, -INFINITY, -INFINITY};
#pragma unroll
            for (int nt = 0; nt < 16; ++nt)
#pragma unroll
                for (int rg = 0; rg < 4; ++rg) rmax[rg] = fmaxf(rmax[rg], sc[nt][rg]);
#pragma unroll
            for (int d = 1; d < 16; d <<= 1)
#pragma unroll
                for (int rg = 0; rg < 4; ++rg)
                    rmax[rg] = fmaxf(rmax[rg], __shfl_xor(rmax[rg], d));
            float rsum[4] = {0.f, 0.f, 0.f, 0.f};
#pragma unroll
            for (int nt = 0; nt < 16; ++nt) {
#pragma unroll
                for (int rg = 0; rg < 4; ++rg) {
                    float p = __expf((sc[nt][rg] - rmax[rg]) * 0.125f);
                    rsum[rg] += p;
                    P[(pl0 + q * 4 + rg) * TLD + nt * 16 + fr] = f2bf(p);
                }
            }
#pragma unroll
            for (int d = 1; d < 16; d <<= 1)
#pragma unroll
                for (int rg = 0; rg < 4; ++rg) rsum[rg] += __shfl_xor(rsum[rg], d);

            // V-peer LDS write (loads have been in flight under QK+softmax)
            if (vq != rs) {
                const int vp = vq << 1;
#pragma unroll
                for (int s8 = 0; s8 < 8; ++s8) {
                    int vs = (s8 + vp) & 7;
                    *(uint4*)&Vt[vd * TLD + vq * 64 + vs * 8] = vb4[vs];
                }
            }
            __syncthreads();                       // Vt complete before PV

            floatx4 o[4];
#pragma unroll
            for (int nt = 0; nt < 4; ++nt) o[nt] = (floatx4){0.f, 0.f, 0.f, 0.f};
#pragma unroll
            for (int kt = 0; kt < 8; ++kt) {
                short8 a = *(const short8*)&P[(pl0 + fr) * TLD + kt * 32 + fk];
#pragma unroll
                for (int nt = 0; nt < 4; ++nt) {
                    short8 b = *(const short8*)&Vt[(nt * 16 + fr) * TLD + kt * 32 + fk];
                    o[nt] = __builtin_amdgcn_mfma_f32_16x16x32_bf16(
                        a, b, o[nt], 0, 0, 0);
                }
            }
            float linv[4];
#pragma unroll
            for (int rg = 0; rg < 4; ++rg) linv[rg] = 1.f / rsum[rg];
#pragma unroll
            for (int nt = 0; nt < 4; ++nt)
#pragma unroll
                for (int rg = 0; rg < 4; ++rg) {
                    int row = m0g + q * 4 + rg;
                    st2_wt(AOcur + (size_t)row * 1024 + h * 64 + nt * 16 + fr,
                           f2bf(o[nt][rg] * linv[rg]));
                }
        }

        // ------ per-rs grid barrier: arrive / prefetch-next / wait ------
        // 16 WGs (all heads, same rs) share counter bar[960 + rs*16].
        rel_drain();
        __syncthreads();
        if (tid == 0)                              // arrive
            __hip_atomic_fetch_add(bar + 960 + rs * 16, 1u,
                    __ATOMIC_RELAXED, __HIP_MEMORY_SCOPE_AGENT);
        const bool more = (t0 + 1 < nsteps);
        if (more) {                                // barrier-independent work
            stage_W(Wc, h, 0,  sm.st.Wb[0], wave, lane);   // next i >= 2
            stage_W(Wc, h, 64, sm.st.Wb[0] + 8192, wave, lane);
            const ushort_t* Qrow = Qchunk + (size_t)(i + 1 - w0) * WIN
                + (size_t)(m0g + fr) * 1024 + h * 64;
            qf0 = *(const short8*)(Qrow);
            qf1 = *(const short8*)(Qrow + 32);
        }
        if (tid == 0 && more) {                    // wait (skipped on final step)
            while (__hip_atomic_load(bar + 960 + rs * 16, __ATOMIC_RELAXED,
                                     __HIP_MEMORY_SCOPE_AGENT) < 16u * s)
                __builtin_amdgcn_s_sleep(1);
        }
        __syncthreads();
        if (more) {                                // AO_i rows [rs*64,+64) visible
            const ushort_t* An = AOb + (size_t)(i & 7) * WIN
                + (size_t)rs * 64 * 1024;
            stage_A(An, 0,  sm.st.Ab[0], wave, lane);
            stage_A(An, 64, sm.st.Ab[0] + 4096, wave, lane);
        }
    }
}

// ===========================================================================
// Fused cooperative kernel: grid 256 WGs x 256 thr, 1 WG/CU.
// XCD role partition (x = wg&7 assumed = XCD id; perf-only assumption):
//   x in {0,1}: scan WGs; h = (x<<3)|(y>>2); rs = y&3 (4 rs of a head
//               co-located on one XCD -> exchange stays in that L2).
//   x in {2..7}: 192 helpers computing phase-1 for chunk c+1.
// ===========================================================================
struct GemmSmem { ushort_t As[128 * 32]; ushort_t Bs[128 * 32]; };
union FusedSmem { ScanSmem scan; GemmSmem gem; AttnShared att; };

__global__ __launch_bounds__(256, 1) void fused_k(
    const ushort_t* __restrict__ Qchunk, int i0, int w0, int nsteps,
    const ushort_t* __restrict__ x0, ushort_t* __restrict__ AOb,
    ushort_t* __restrict__ KVx,
    const ushort_t* __restrict__ Wkv, const float* __restrict__ bkv,
    const ushort_t* __restrict__ Wc, const float* __restrict__ bc,
    unsigned* __restrict__ bar, unsigned s0,
    int do_help, int w0n,
    const ushort_t* __restrict__ path_bf,
    const ushort_t* __restrict__ w_in1, const float* __restrict__ b_in1,
    ushort_t* __restrict__ qkv, ushort_t* __restrict__ ao,
    ushort_t* __restrict__ ybuf,
    const ushort_t* __restrict__ w_out1, const float* __restrict__ b_out1,
    const ushort_t* __restrict__ w_lin, const float* __restrict__ b_lin,
    ushort_t* __restrict__ Xc,
    const ushort_t* __restrict__ w_in2, const float* __restrict__ b_in2,
    ushort_t* __restrict__ Qnext, unsigned hs0)
{
    __shared__ FusedSmem sm;
    const int wg = blockIdx.x;
    const int x = wg & 7, y = wg >> 3;

    if (x < 2) {
        const int h  = (x << 3) | (y >> 2);
        const int rs = y & 3;
        scan_body(sm.scan, h, rs,
                  Qchunk, i0, w0, nsteps, x0, AOb, KVx,
                  Wkv, bkv, Wc, bc, bar, s0);
        return;
    }
    if (!do_help) return;

    const int hw = (x - 2) * 32 + y; // 0..191
    const int hg = hw >> 3;          // 24 groups of 8

    // stage 1: qkv = gather(path) @ w_in1^T + b_in1  (384 tiles, 2 per WG)
    for (int t = hw; t < 384; t += 192) {
        int bx = t % 24, by = t / 24;
        gemm_core<true, true>(sm.gem.As, sm.gem.Bs, path_bf, 1024, w0n,
                              w_in1, b_in1, qkv, nullptr, 3072, 1024,
                              by * 128, bx * 128, bx * 128, 0);
    }
    help_bar(bar, hg, hs0);

    // stage 2: sliding attention (512 blocks)
    for (int t = hw; t < 512; t += 192) {
        int rs = t & 3, h = (t >> 2) & 15, b = t >> 6;
        attn_body(sm.att, qkv, ao, rs, h, b);
    }
    help_bar(bar, hg, hs0 + 1);

    // stage 3: y = ao @ w_out1^T + b_out1 (128 tiles)
    for (int t = hw; t < 128; t += 192) {
        int bx = t & 7, by = t >> 3;
        gemm_core<false, true>(sm.gem.As, sm.gem.Bs, ao, 1024, 0,
                               w_out1, b_out1, ybuf, nullptr, 1024, 1024,
                               by * 128, bx * 128, bx * 128, 0);
    }
    help_bar(bar, hg, hs0 + 2);

    // stage 4: X = relu(y @ w_lin^T + b_lin)
    for (int t = hw; t < 128; t += 192) {
        int bx = t & 7, by = t >> 3;
        gemm_core<false, true>(sm.gem.As, sm.gem.Bs, ybuf, 1024, 0,
                               w_lin, b_lin, Xc, nullptr, 1024, 1024,
                               by * 128, bx * 128, bx * 128, 1);
    }
    help_bar(bar, hg, hs0 + 3);

    // stage 5: Qnext = X @ wq^T + bq (rows 0..1023 of w_in2); consumed by
    // the NEXT launch's scan (kernel boundary provides release/acquire).
    for (int t = hw; t < 128; t += 192) {
        int bx = t & 7, by = t >> 3;
        gemm_core<false, true>(sm.gem.As, sm.gem.Bs, Xc, 1024, 0,
                               w_in2, b_in2, Qnext, nullptr, 1024, 1024,
                               by * 128, bx * 128, bx * 128, 0);
    }
}

// ---------------------------------------------------------------------------
extern "C" void kernel_launch(void* const* d_in, const int* in_sizes, int n_in,
                              void* d_out, int out_size, void* d_ws, size_t ws_size,
                              hipStream_t stream)
{
    const float* path   = (const float*)d_in[0];
    const float* w_in1  = (const float*)d_in[1];
    const float* b_in1  = (const float*)d_in[2];
    const float* w_out1 = (const float*)d_in[3];
    const float* b_out1 = (const float*)d_in[4];
    const float* w_lin  = (const float*)d_in[5];
    const float* b_lin  = (const float*)d_in[6];
    const float* w_in2  = (const float*)d_in[7];
    const float* b_in2  = (const float*)d_in[8];
    const float* w_out2 = (const float*)d_in[9];
    const float* b_out2 = (const float*)d_in[10];
    float* out = (float*)d_out;

    // workspace: barriers/bias (32 KB) then bf16 buffers (~78 MB)
    unsigned* bar = (unsigned*)d_ws;                      // 8 KB
    float* bc      = (float*)d_ws + 2048;                 // 2048 fp32
    float* zerosf  = bc + 2048;                           // 1024 fp32
    ushort_t* ws = (ushort_t*)d_ws + 16384;
    ushort_t* path_bf  = ws;                              // 4096*1024
    ushort_t* w_in1_bf = path_bf  + (size_t)4096 * 1024;  // 3072*1024
    ushort_t* w_out1_bf= w_in1_bf + (size_t)3072 * 1024;
    ushort_t* w_lin_bf = w_out1_bf+ (size_t)1024 * 1024;
    ushort_t* w_in2_bf = w_lin_bf + (size_t)1024 * 1024;  // 3072*1024
    ushort_t* w_out2_bf= w_in2_bf + (size_t)3072 * 1024;
    ushort_t* WoT_bf   = w_out2_bf+ (size_t)1024 * 1024;  // 1024*1024
    ushort_t* Wc_bf    = WoT_bf   + (size_t)1024 * 1024;  // 2048*1024
    ushort_t* qkv_bf   = Wc_bf    + (size_t)2048 * 1024;  // 2048*3072
    ushort_t* ao_bf    = qkv_bf   + (size_t)2048 * 3072;  // 2048*1024
    ushort_t* ybuf_bf  = ao_bf    + (size_t)2048 * 1024;  // 2048*1024
    ushort_t* Xbuf     = ybuf_bf  + (size_t)2048 * 1024;  // 2048*1024
    ushort_t* Qb0      = Xbuf     + (size_t)2048 * 1024;  // 2048*1024
    ushort_t* Qb1      = Qb0      + (size_t)2048 * 1024;  // 2048*1024
    ushort_t* AOb      = Qb1      + (size_t)2048 * 1024;  // 8 x 256*1024
    ushort_t* x0buf    = AOb + 8 * WIN;                   // 256*1024
    ushort_t* dummy    = x0buf + WIN;                     // 256*1024
    ushort_t* KVx      = dummy + WIN;                     // 8 x 16 x 32768 (8 MB)
    ushort_t* Qb[2] = {Qb0, Qb1};

    hipMemsetAsync(bar, 0, 8192, stream);
    hipMemsetAsync(zerosf, 0, 1024 * sizeof(float), stream);

    cast_bf_k<<<4096, 256, 0, stream>>>(path,  path_bf,  4096 * 1024);
    cast_bf_k<<<3072, 256, 0, stream>>>(w_in1, w_in1_bf, 3072 * 1024);
    cast_bf_k<<<1024, 256, 0, stream>>>(w_out1, w_out1_bf, 1024 * 1024);
    cast_bf_k<<<1024, 256, 0, stream>>>(w_lin, w_lin_bf, 1024 * 1024);
    cast_bf_k<<<3072, 256, 0, stream>>>(w_in2, w_in2_bf, 3072 * 1024);
    cast_bf_k<<<1024, 256, 0, stream>>>(w_out2, w_out2_bf, 1024 * 1024);

    // fused scan weights: Wc = Wkv @ Wo  (bf16), bc = bkv + Wkv @ bo (fp32)
    transpose_k<<<dim3(16, 16), 256, 0, stream>>>(w_out2_bf, WoT_bf);
    bc_k<<<8, 256, 0, stream>>>(w_in2, b_in2, b_out2, bc);
    gemm_bf_k<<<dim3(8, 16), 256, 0, stream>>>(
        w_in2_bf + (size_t)1024 * 1024, 1024, WoT_bf, zerosf,
        Wc_bf, nullptr, 1024, 1024, 0);

    // ---- Phase 1 for chunk 0 (separate kernels; later chunks are fused) ----
    gemm_qkv_k<<<dim3(24, 16), 256, 0, stream>>>(
        path_bf, w_in1_bf, b_in1, qkv_bf, 0);
    attn_mfma_k<<<dim3(4, NH, CHUNK), 256, 0, stream>>>(qkv_bf, ao_bf);
    gemm_bf_k<<<dim3(8, 16), 256, 0, stream>>>(
        ao_bf, 1024, w_out1_bf, b_out1, ybuf_bf, nullptr, 1024, 1024, 0);
    gemm_bf_k<<<dim3(8, 16), 256, 0, stream>>>(
        ybuf_bf, 1024, w_lin_bf, b_lin, Xbuf, nullptr, 1024, 1024, 1);
    gemm_bf_k<<<dim3(8, 16), 256, 0, stream>>>(
        Xbuf, 1024, w_in2_bf, b_in2, Qb[0], nullptr, 1024, 1024, 0);
    (void)hipMemcpyAsync(x0buf, Xbuf, WIN * sizeof(ushort_t),
                         hipMemcpyDeviceToDevice, stream);

    unsigned sbase = 1;
    for (int c = 0; c < NCHUNK; ++c) {
        int w0 = c * CHUNK;
        int i0 = (c == 0) ? 1 : w0;
        int nsteps = (c == 0) ? CHUNK - 1 : CHUNK;
        int do_help = (c + 1 < NCHUNK) ? 1 : 0;
        int w0n = (c + 1) * CHUNK;
        unsigned hs0 = (unsigned)(c * 4 + 1);
        const ushort_t* Qcur = Qb[c & 1];
        ushort_t* Qnext = Qb[(c + 1) & 1];
        const ushort_t* x0P = x0buf;
        ushort_t* AObP = AOb;
        ushort_t* KVxP = KVx;
        const ushort_t* WkvP = w_in2_bf + (size_t)1024 * 1024;
        const float* bkvP = b_in2 + 1024;
        const ushort_t* WcP = Wc_bf;
        const float* bcP = bc;
        unsigned* barP = bar;
        unsigned sb = sbase;
        const ushort_t* pathP = path_bf;
        const ushort_t* win1P = w_in1_bf;
        const float* bin1P = b_in1;
        ushort_t* qkvP = qkv_bf;
        ushort_t* aoP = ao_bf;
        ushort_t* ybufP = ybuf_bf;
        const ushort_t* wout1P = w_out1_bf;
        const float* bout1P = b_out1;
        const ushort_t* wlinP = w_lin_bf;
        const float* blinP = b_lin;
        ushort_t* XP = Xbuf;
        const ushort_t* win2P = w_in2_bf;
        const float* bin2P = b_in2;
        void* args[] = {&Qcur, &i0, &w0, &nsteps, &x0P, &AObP, &KVxP,
                        &WkvP, &bkvP, &WcP, &bcP, &barP, &sb,
                        &do_help, &w0n, &pathP, &win1P, &bin1P,
                        &qkvP, &aoP, &ybufP, &wout1P, &bout1P,
                        &wlinP, &blinP, &XP, &win2P, &bin2P, &Qnext, &hs0};
        hipLaunchCooperativeKernel((void*)fused_k, dim3(256), dim3(256),
                                   args, 0, stream);
        sbase += (unsigned)nsteps;
    }

    // final out-projection: out = AO_239 @ Wo^T + bo  (fp32 to d_out)
    gemm_bf_k<<<dim3(8, 2), 256, 0, stream>>>(
        AOb + (size_t)((N_WIN - 1) & 7) * WIN, 1024, w_out2_bf, b_out2,
        dummy, out, 1024, 1024, 0);
}

// Round 11
// 5970.947 us; speedup vs baseline: 1.0540x; 1.0540x over previous
//
#include <hip/hip_runtime.h>
#include <math.h>

// Problem constants
#define D_MODEL 1024
#define N_WIN   240
#define TOK     256
#define NH      16
#define DH      64
#define CHUNK   8
#define NCHUNK  30
#define WIN     ((size_t)TOK * D_MODEL)

typedef unsigned short ushort_t;
typedef unsigned long long ull_t;
typedef __attribute__((ext_vector_type(8))) short short8;
typedef __attribute__((ext_vector_type(4))) float floatx4;

__device__ __forceinline__ ushort_t f2bf(float f) {   // RNE
    unsigned u = __float_as_uint(f);
    unsigned lsb = (u >> 16) & 1u;
    u += 0x7fffu + lsb;
    return (ushort_t)(u >> 16);
}

// ---------------------------------------------------------------------------
// Coherence: write-through (sc1) -> IC for every cross-WG consumed buffer;
// readers' L2s invalidated at launch start; 8-slot rotation guarantees no
// read-before-write within a launch. Qchunk double-buffered across launches.
//
// Round-23 = REVERT to round-21 (verified 6.05 ms / 186 us per dispatch).
// Round-22's V-register-gather caused scratch spills (WRITE_SIZE +7 MB,
// +26 us/dispatch) — exact undo. Structure:
//  - KV staged loop: BK=128 chunks (8 iters), A/W 3-deep, single barrier
//    per chunk (write at t, last read t-2, separated by barrier t-1).
//  - Per-rs 16-WG grid barrier (arrive / W+Q prefetch / wait).
//  - Head barrier arrive/wait split with own-slice direct LDS write.
// Arithmetic bit-identical (absmax canary 6.430412e-13).
// ---------------------------------------------------------------------------
__device__ __forceinline__ void st2_wt(ushort_t* p, ushort_t v) {
    unsigned vv = v;
    asm volatile("global_store_short %0, %1, off sc1"
                 :: "v"(p), "v"(vv) : "memory");
}
__device__ __forceinline__ void st8_wt(ushort_t* p, ushort4 v) {
    ull_t dv = (ull_t)((unsigned)v.x | ((unsigned)v.y << 16))
             | ((ull_t)((unsigned)v.z | ((unsigned)v.w << 16)) << 32);
    asm volatile("global_store_dwordx2 %0, %1, off sc1"
                 :: "v"(p), "v"(dv) : "memory");
}
__device__ __forceinline__ void rel_drain() {
    asm volatile("s_waitcnt vmcnt(0)" ::: "memory");
}

// async global->LDS, 16B per lane (GEMM staging)
#define GLDS(g, l) __builtin_amdgcn_global_load_lds( \
    (const __attribute__((address_space(1))) unsigned int*)(g), \
    (__attribute__((address_space(3))) unsigned int*)(l), 16, 0, 0)

// ---------------------------------------------------------------------------
// Helper barrier among the 192 phase-1 helper WGs (24 subs x 8 arrivals).
// ---------------------------------------------------------------------------
__device__ __forceinline__ void help_bar(unsigned* base, int g, unsigned s)
{
    rel_drain();
    __syncthreads();
    if (threadIdx.x == 0) {
        unsigned old = __hip_atomic_fetch_add(base + 1024 + g * 32, 1u,
                __ATOMIC_RELAXED, __HIP_MEMORY_SCOPE_AGENT);
        if (old == 8u * s - 1u) {
            unsigned r = __hip_atomic_fetch_add(base + 1800, 1u,
                    __ATOMIC_RELAXED, __HIP_MEMORY_SCOPE_AGENT);
            if (r == 24u * s - 1u)
                __hip_atomic_store(base + 1832, s, __ATOMIC_RELAXED,
                                   __HIP_MEMORY_SCOPE_AGENT);
        }
        while (__hip_atomic_load(base + 1832, __ATOMIC_RELAXED,
                                 __HIP_MEMORY_SCOPE_AGENT) < s)
            __builtin_amdgcn_s_sleep(1);
    }
    __syncthreads();
}

// ---------------------------------------------------------------------------
// fp32 -> bf16 cast
// ---------------------------------------------------------------------------
__global__ __launch_bounds__(256) void cast_bf_k(
    const float* __restrict__ s, ushort_t* __restrict__ d, int n)
{
    int i = (blockIdx.x * 256 + threadIdx.x) * 4;
    if (i >= n) return;
    float4 v = *(const float4*)(s + i);
    ushort4 o;
    o.x = f2bf(v.x); o.y = f2bf(v.y); o.z = f2bf(v.z); o.w = f2bf(v.w);
    *(ushort4*)(d + i) = o;
}

// 64x64-tile bf16 transpose: dst[c][r] = src[r][c], both 1024x1024
__global__ __launch_bounds__(256) void transpose_k(
    const ushort_t* __restrict__ src, ushort_t* __restrict__ dst)
{
    __shared__ ushort_t t[64][65];
    const int bx = blockIdx.x * 64, by = blockIdx.y * 64;
    const int c = threadIdx.x & 63, r0 = threadIdx.x >> 6;
#pragma unroll
    for (int k = 0; k < 16; ++k) {
        int r = r0 + k * 4;
        t[r][c] = src[(size_t)(by + r) * 1024 + bx + c];
    }
    __syncthreads();
#pragma unroll
    for (int k = 0; k < 16; ++k) {
        int r = r0 + k * 4;
        dst[(size_t)(bx + r) * 1024 + by + c] = t[c][r];
    }
}

// bc[n] = b_in2[1024+n] + dot(w_in2 row (1024+n), b_out2), fp32, n in [0,2048)
__global__ __launch_bounds__(256) void bc_k(
    const float* __restrict__ w_in2, const float* __restrict__ b_in2,
    const float* __restrict__ b_out2, float* __restrict__ bc)
{
    int n = blockIdx.x * 256 + threadIdx.x;
    const float* row = w_in2 + (size_t)(1024 + n) * 1024;
    float s = b_in2[1024 + n];
    for (int j = 0; j < 1024; j += 4) {
        float4 w = *(const float4*)(row + j);
        float4 b = *(const float4*)(b_out2 + j);
        s += w.x * b.x + w.y * b.y + w.z * b.z + w.w * b.w;
    }
    bc[n] = s;
}

// ---------------------------------------------------------------------------
// bf16 MFMA GEMM core (m97 structure), 128x128 tile, BK=32.
// ---------------------------------------------------------------------------
template<bool GATHER, bool WT>
__device__ __forceinline__ void gemm_core(
    ushort_t* As, ushort_t* Bs,
    const ushort_t* __restrict__ A, int lda, int w0,
    const ushort_t* __restrict__ W, const float* __restrict__ bias,
    ushort_t* __restrict__ Cb, float* __restrict__ Cf, int ldc,
    int K, int m0, int n0, int co, int relu)
{
    const int tid = threadIdx.x;
    const int wave = tid >> 6, lane = tid & 63;
    const int wm = wave & 1, wn = wave >> 1;

    int r0 = m0 + (tid >> 2), r1 = r0 + 64;
    if (GATHER) {
        r0 = (w0 + (r0 >> 8)) * 16 + (r0 & 255);
        r1 = (w0 + (r1 >> 8)) * 16 + (r1 & 255);
    }
    const int kcol = (tid & 3) * 8;
    const ushort_t* gA0 = A + (size_t)r0 * lda + kcol;
    const ushort_t* gA1 = A + (size_t)r1 * lda + kcol;
    const ushort_t* pW  = W + (size_t)n0 * K;
    const ushort_t* gB0 = pW + (size_t)(tid >> 2) * K + kcol;
    const ushort_t* gB1 = gB0 + (size_t)64 * K;
    ushort_t* lA = As + wave * 512;
    ushort_t* lB = Bs + wave * 512;

    floatx4 acc[4][4];
#pragma unroll
    for (int i = 0; i < 4; ++i)
#pragma unroll
        for (int j = 0; j < 4; ++j) acc[i][j] = (floatx4){0.f, 0.f, 0.f, 0.f};

    const int fr = lane & 15, fk = (lane >> 4) * 8;
    const int arow = (wm * 64 + fr) * 32 + fk;
    const int brow = (wn * 64 + fr) * 32 + fk;

    for (int k0 = 0; k0 < K; k0 += 32) {
        GLDS(gA0 + k0, lA);
        GLDS(gA1 + k0, lA + 2048);
        GLDS(gB0 + k0, lB);
        GLDS(gB1 + k0, lB + 2048);
        __syncthreads();
        short8 a[4], b[4];
#pragma unroll
        for (int mi = 0; mi < 4; ++mi) a[mi] = *(const short8*)&As[arow + mi * 512];
#pragma unroll
        for (int ni = 0; ni < 4; ++ni) b[ni] = *(const short8*)&Bs[brow + ni * 512];
#pragma unroll
        for (int mi = 0; mi < 4; ++mi)
#pragma unroll
            for (int ni = 0; ni < 4; ++ni)
                acc[mi][ni] = __builtin_amdgcn_mfma_f32_16x16x32_bf16(
                    a[mi], b[ni], acc[mi][ni], 0, 0, 0);
        __syncthreads();
    }

    const int crq = (lane >> 4) * 4;
    const int ccol = lane & 15;
#pragma unroll
    for (int mi = 0; mi < 4; ++mi) {
#pragma unroll
        for (int ni = 0; ni < 4; ++ni) {
            int lc = wn * 64 + ni * 16 + ccol;
            float bz = bias[n0 + lc];
#pragma unroll
            for (int rg = 0; rg < 4; ++rg) {
                int row = m0 + wm * 64 + mi * 16 + crq + rg;
                float v = acc[mi][ni][rg] + bz;
                if (relu) v = fmaxf(v, 0.f);
                size_t off = (size_t)row * ldc + co + lc;
                if (Cb) {
                    if (WT) st2_wt(Cb + off, f2bf(v));
                    else    Cb[off] = f2bf(v);
                }
                if (Cf) Cf[off] = v;
            }
        }
    }
}

__global__ __launch_bounds__(256) void gemm_bf_k(
    const ushort_t* __restrict__ A, int lda,
    const ushort_t* __restrict__ W, const float* __restrict__ bias,
    ushort_t* __restrict__ Cb, float* __restrict__ Cf, int ldc,
    int K, int relu)
{
    __shared__ ushort_t As[128 * 32];
    __shared__ ushort_t Bs[128 * 32];
    gemm_core<false, false>(As, Bs, A, lda, 0, W, bias, Cb, Cf, ldc, K,
                            blockIdx.y * 128, blockIdx.x * 128, blockIdx.x * 128, relu);
}

__global__ __launch_bounds__(256) void gemm_qkv_k(
    const ushort_t* __restrict__ path_bf, const ushort_t* __restrict__ W,
    const float* __restrict__ bias, ushort_t* __restrict__ Cb, int w0)
{
    __shared__ ushort_t As[128 * 32];
    __shared__ ushort_t Bs[128 * 32];
    gemm_core<true, false>(As, Bs, path_bf, 1024, w0, W, bias, Cb, nullptr, 3072, 1024,
                           blockIdx.y * 128, blockIdx.x * 128, blockIdx.x * 128, 0);
}

// ---------------------------------------------------------------------------
// Phase-1 MFMA attention body (O stores write-through for fused consumers).
// ---------------------------------------------------------------------------
#define PLD 260
#define VLD 132

struct AttnShared {
    ushort_t P[64 * PLD];
    ushort_t VT[64 * VLD];
    float    l[64];
};

__device__ void attn_body(AttnShared& sh,
    const ushort_t* __restrict__ qkv, ushort_t* __restrict__ ao,
    int rs, int h, int b)
{
    const ushort_t* base = qkv + (size_t)b * TOK * 3072;
    const ushort_t* Q = base;
    const ushort_t* K = base + 1024;
    const ushort_t* V = base + 2048;
    ushort_t* O = ao + (size_t)b * TOK * 1024;
    const int ldq = 3072, ldkv = 3072, ldo = 1024;
    const int tid = threadIdx.x;
    const int wave = tid >> 6, lane = tid & 63;
    const int fr = lane & 15, q = lane >> 4, fk = q * 8;
    const ushort_t* Qh = Q + (size_t)(rs * 64) * ldq + h * 64;
    const ushort_t* Kh = K + h * 64;
    const ushort_t* Vh = V + h * 64;
    const int m0 = wave * 16;

    floatx4 s[16];
#pragma unroll
    for (int nt = 0; nt < 16; ++nt) s[nt] = (floatx4){0.f, 0.f, 0.f, 0.f};
#pragma unroll
    for (int kc = 0; kc < 64; kc += 32) {
        short8 a = *(const short8*)(Qh + (size_t)(m0 + fr) * ldq + kc + fk);
#pragma unroll
        for (int nt = 0; nt < 16; ++nt) {
            short8 b2 = *(const short8*)(Kh + (size_t)(nt * 16 + fr) * ldkv + kc + fk);
            s[nt] = __builtin_amdgcn_mfma_f32_16x16x32_bf16(a, b2, s[nt], 0, 0, 0);
        }
    }

    float rmax[4] = {-INFINITY, -INFINITY, -INFINITY, -INFINITY};
#pragma unroll
    for (int nt = 0; nt < 16; ++nt)
#pragma unroll
        for (int rg = 0; rg < 4; ++rg) rmax[rg] = fmaxf(rmax[rg], s[nt][rg]);
#pragma unroll
    for (int d = 1; d < 16; d <<= 1)
#pragma unroll
        for (int rg = 0; rg < 4; ++rg)
            rmax[rg] = fmaxf(rmax[rg], __shfl_xor(rmax[rg], d));

    float rsum[4] = {0.f, 0.f, 0.f, 0.f};
#pragma unroll
    for (int nt = 0; nt < 16; ++nt) {
#pragma unroll
        for (int rg = 0; rg < 4; ++rg) {
            float p = __expf((s[nt][rg] - rmax[rg]) * 0.125f);
            rsum[rg] += p;
            sh.P[(m0 + q * 4 + rg) * PLD + nt * 16 + fr] = f2bf(p);
        }
    }
#pragma unroll
    for (int d = 1; d < 16; d <<= 1)
#pragma unroll
        for (int rg = 0; rg < 4; ++rg) rsum[rg] += __shfl_xor(rsum[rg], d);
    if (fr == 0) {
#pragma unroll
        for (int rg = 0; rg < 4; ++rg) sh.l[m0 + q * 4 + rg] = rsum[rg];
    }
    __syncthreads();

    floatx4 o[4];
#pragma unroll
    for (int i = 0; i < 4; ++i) o[i] = (floatx4){0.f, 0.f, 0.f, 0.f};

#pragma unroll
    for (int half = 0; half < 2; ++half) {
        {
            int r = tid & 127, cp = tid >> 7;
            const ushort_t* vrow = Vh + (size_t)(half * 128 + r) * ldkv + cp * 32;
#pragma unroll
            for (int c = 0; c < 4; ++c) {
                uint4 pk = *(const uint4*)(vrow + c * 8);
                int d0 = cp * 32 + c * 8;
                sh.VT[(d0 + 0) * VLD + r] = (ushort_t)(pk.x & 0xffff);
                sh.VT[(d0 + 1) * VLD + r] = (ushort_t)(pk.x >> 16);
                sh.VT[(d0 + 2) * VLD + r] = (ushort_t)(pk.y & 0xffff);
                sh.VT[(d0 + 3) * VLD + r] = (ushort_t)(pk.y >> 16);
                sh.VT[(d0 + 4) * VLD + r] = (ushort_t)(pk.z & 0xffff);
                sh.VT[(d0 + 5) * VLD + r] = (ushort_t)(pk.z >> 16);
                sh.VT[(d0 + 6) * VLD + r] = (ushort_t)(pk.w & 0xffff);
                sh.VT[(d0 + 7) * VLD + r] = (ushort_t)(pk.w >> 16);
            }
        }
        __syncthreads();
#pragma unroll
        for (int ks = 0; ks < 4; ++ks) {
            short8 a = *(const short8*)&sh.P[(m0 + fr) * PLD + half * 128 + ks * 32 + fk];
#pragma unroll
            for (int nt2 = 0; nt2 < 4; ++nt2) {
                short8 b2 = *(const short8*)&sh.VT[(nt2 * 16 + fr) * VLD + ks * 32 + fk];
                o[nt2] = __builtin_amdgcn_mfma_f32_16x16x32_bf16(a, b2, o[nt2], 0, 0, 0);
            }
        }
        __syncthreads();
    }

    float linv[4];
#pragma unroll
    for (int rg = 0; rg < 4; ++rg) linv[rg] = 1.f / sh.l[m0 + q * 4 + rg];
#pragma unroll
    for (int nt2 = 0; nt2 < 4; ++nt2)
#pragma unroll
        for (int rg = 0; rg < 4; ++rg) {
            int row = rs * 64 + m0 + q * 4 + rg;
            st2_wt(O + (size_t)row * ldo + h * 64 + nt2 * 16 + fr,
                   f2bf(o[nt2][rg] * linv[rg]));
        }
    __syncthreads();   // protect sh.l/sh.P across back-to-back calls
}

__global__ __launch_bounds__(256) void attn_mfma_k(
    const ushort_t* __restrict__ qkv, ushort_t* __restrict__ ao)
{
    __shared__ AttnShared sh;
    attn_body(sh, qkv, ao, blockIdx.x, blockIdx.y, blockIdx.z);
}

// ===========================================================================
// Scan body (round-23 = round-21): BK=128 single-barrier KV loop (A/W
// 3-deep), per-rs 16-WG grid barrier, arrive/wait splits with W/Q prefetch
// and own-slice LDS write; final-step grid wait skipped.
// ===========================================================================
#define KLD 76    // K stride (152 B) — conflict-free QK reads
#define TLD 264   // Vt / P stride (528 B)

struct ScanSmem {
    union {
        struct { ushort_t Ab[3][8192]; ushort_t Wb[3][16384]; } st;   // 144 KB
        struct { ushort_t Kl[256 * KLD]; ushort_t Vt[64 * TLD];
                 ushort_t P[64 * TLD]; } at;                          // 104 KB
    };
};

__device__ __forceinline__ void stage_A(
    const ushort_t* __restrict__ A64, int k0, ushort_t* __restrict__ Ad,
    int wave, int lane)
{
    // A sub-chunk: 64 rows x 64 cols (8 KB) = 2 GLDS per wave
#pragma unroll
    for (int t = 0; t < 2; ++t) {
        int j = wave * 128 + t * 64 + lane;        // 16B slot index
        int row = j >> 3;
        int blk = (j & 7) ^ (row & 7);             // inverse swizzle on source
        GLDS(A64 + (size_t)row * 1024 + k0 + blk * 8,
             Ad + wave * 1024 + t * 512);
    }
}

__device__ __forceinline__ void stage_W(
    const ushort_t* __restrict__ Wsel, int h, int k0,
    ushort_t* __restrict__ Wd, int wave, int lane)
{
    // W sub-chunk: 128 rows x 64 cols (16 KB) = 4 GLDS per wave
#pragma unroll
    for (int t = 0; t < 4; ++t) {
        int j = wave * 256 + t * 64 + lane;
        int r = j >> 3;
        int blk = (j & 7) ^ (r & 7);
        int n = ((r >> 6) << 10) + h * 64 + (r & 63);
        GLDS(Wsel + (size_t)n * 1024 + k0 + blk * 8,
             Wd + wave * 2048 + t * 512);
    }
}

__device__ void scan_body(
    ScanSmem& sm, int h, int rs,
    const ushort_t* __restrict__ Qchunk, int i0, int w0, int nsteps,
    const ushort_t* __restrict__ x0, ushort_t* __restrict__ AOb,
    ushort_t* __restrict__ KVx,
    const ushort_t* __restrict__ Wkv, const float* __restrict__ bkv,
    const ushort_t* __restrict__ Wc, const float* __restrict__ bc,
    unsigned* __restrict__ bar, unsigned s0)
{
    const int tid = threadIdx.x;
    const int wave = tid >> 6, lane = tid & 63;
    const int fr = lane & 15, q = lane >> 4, fk = q * 8;
    const int m0g = rs * 64 + wave * 16;

    // per-wave bias hoist: dims = (wave&1)*32 + nt*16 + fr;
    // waves 0,1 -> K section, waves 2,3 -> V section.
    const int dbofs = (wave < 2 ? 0 : 1024) + h * 64 + (wave & 1) * 32;
    float bK1[2], bC1[2];
#pragma unroll
    for (int nt = 0; nt < 2; ++nt) {
        bK1[nt] = bkv[dbofs + nt * 16 + fr];
        bC1[nt] = bc[dbofs + nt * 16 + fr];
    }

    ushort_t* Kl = sm.at.Kl;
    ushort_t* Vt = sm.at.Vt;
    ushort_t* P  = sm.at.P;

    short8 qf0, qf1;
    // first-step prologue: W chunk 0 (both subs) + Q + A chunk 0 (both subs)
    {
        const int i = i0;
        const ushort_t* Wsel0 = (i == 1) ? Wkv : Wc;
        stage_W(Wsel0, h, 0,  sm.st.Wb[0], wave, lane);
        stage_W(Wsel0, h, 64, sm.st.Wb[0] + 8192, wave, lane);
        const ushort_t* Qrow = Qchunk + (size_t)(i - w0) * WIN
            + (size_t)(m0g + fr) * 1024 + h * 64;
        qf0 = *(const short8*)(Qrow);
        qf1 = *(const short8*)(Qrow + 32);
        const ushort_t* Asrc0 = (i == 1) ? x0
            : AOb + (size_t)((i - 1) & 7) * WIN;
        stage_A(Asrc0 + (size_t)rs * 64 * 1024, 0,  sm.st.Ab[0], wave, lane);
        stage_A(Asrc0 + (size_t)rs * 64 * 1024, 64, sm.st.Ab[0] + 4096, wave, lane);
    }

    unsigned s = s0;
    for (int t0 = 0; t0 < nsteps; ++t0, ++s) {
        const int i = i0 + t0;
        const ushort_t* Asrc = (i == 1) ? x0
            : AOb + (size_t)((i - 1) & 7) * WIN;
        const ushort_t* Wsel = (i == 1) ? Wkv : Wc;
        const ushort_t* A64 = Asrc + (size_t)rs * 64 * 1024;
        ushort_t* KVs = KVx + (size_t)(i & 7) * (NH * 32768) + h * 32768;

        // ---------- KV build: keys [rs*64,+64) x 128 dims, BK=128 ----------
        floatx4 acc[4][2];
#pragma unroll
        for (int mt = 0; mt < 4; ++mt)
#pragma unroll
            for (int nt = 0; nt < 2; ++nt)
                acc[mt][nt] = (floatx4){0.f, 0.f, 0.f, 0.f};

        // Single-barrier pipeline, 3-deep both: buf[(t+1)%3] written at iter
        // t, last read at iter t-2 — all waves passed barrier t-1 first.
#pragma unroll 1
        for (int t = 0; t < 8; ++t) {
            if (t < 7) {
                stage_A(A64, (t + 1) * 128,      sm.st.Ab[(t + 1) % 3], wave, lane);
                stage_A(A64, (t + 1) * 128 + 64, sm.st.Ab[(t + 1) % 3] + 4096, wave, lane);
                stage_W(Wsel, h, (t + 1) * 128,      sm.st.Wb[(t + 1) % 3], wave, lane);
                stage_W(Wsel, h, (t + 1) * 128 + 64, sm.st.Wb[(t + 1) % 3] + 8192, wave, lane);
                asm volatile("s_waitcnt vmcnt(12)" ::: "memory");
            } else {
                asm volatile("s_waitcnt vmcnt(0)" ::: "memory");
            }
            __builtin_amdgcn_s_barrier();          // chunk t resident (all waves)
            const ushort_t* Ac  = sm.st.Ab[t % 3];
            const ushort_t* Wc_ = sm.st.Wb[t % 3];
#pragma unroll
            for (int sub = 0; sub < 2; ++sub) {
                const ushort_t* Acs = Ac  + sub * 4096;
                const ushort_t* Wcs = Wc_ + sub * 8192;
#pragma unroll
                for (int kh = 0; kh < 2; ++kh) {
                    const int pb = (((kh << 2) + q) ^ (fr & 7)) * 8;
                    short8 a[4];
#pragma unroll
                    for (int mt = 0; mt < 4; ++mt)
                        a[mt] = *(const short8*)&Acs[(mt * 16 + fr) * 64 + pb];
#pragma unroll
                    for (int nt = 0; nt < 2; ++nt) {
                        short8 b = *(const short8*)
                            &Wcs[(wave * 32 + nt * 16 + fr) * 64 + pb];
#pragma unroll
                        for (int mt = 0; mt < 4; ++mt)
                            acc[mt][nt] = __builtin_amdgcn_mfma_f32_16x16x32_bf16(
                                a[mt], b, acc[mt][nt], 0, 0, 0);
                    }
                }
            }
        }
        __builtin_amdgcn_s_barrier();              // all compute done before
                                                   // epilogue aliases staging
        // ---- exchange: write full K/V slice to global slot (for peers) ----
        ushort_t* Kx = KVs;                        // [key][64]
        ushort_t* Vx = KVs + 16384;                // [dim][256]
#pragma unroll
        for (int mt = 0; mt < 4; ++mt) {
#pragma unroll
            for (int nt = 0; nt < 2; ++nt) {
                const float bz = (i == 1) ? bK1[nt] : bC1[nt];
                const int d = (wave & 1) * 32 + nt * 16 + fr;
                if (wave < 2) {
#pragma unroll
                    for (int rg = 0; rg < 4; ++rg) {
                        const int key = rs * 64 + mt * 16 + q * 4 + rg;
                        st2_wt(Kx + key * 64 + d, f2bf(acc[mt][nt][rg] + bz));
                    }
                } else {
                    ushort4 pv;
                    pv.x = f2bf(acc[mt][nt][0] + bz);
                    pv.y = f2bf(acc[mt][nt][1] + bz);
                    pv.z = f2bf(acc[mt][nt][2] + bz);
                    pv.w = f2bf(acc[mt][nt][3] + bz);
                    st8_wt(Vx + d * 256 + rs * 64 + mt * 16 + q * 4, pv);
                }
            }
        }
        rel_drain();
        __syncthreads();
        if (tid == 0)                              // head arrive
            __hip_atomic_fetch_add(bar + 384 + h * 32, 1u,
                    __ATOMIC_RELAXED, __HIP_MEMORY_SCOPE_AGENT);

        // own-slice direct LDS write (bit-identical to the gather path)
#pragma unroll
        for (int mt = 0; mt < 4; ++mt) {
#pragma unroll
            for (int nt = 0; nt < 2; ++nt) {
                const float bz = (i == 1) ? bK1[nt] : bC1[nt];
                const int d = (wave & 1) * 32 + nt * 16 + fr;
                if (wave < 2) {
#pragma unroll
                    for (int rg = 0; rg < 4; ++rg) {
                        const int key = rs * 64 + mt * 16 + q * 4 + rg;
                        Kl[key * KLD + d] = f2bf(acc[mt][nt][rg] + bz);
                    }
                } else {
                    ushort4 pv;
                    pv.x = f2bf(acc[mt][nt][0] + bz);
                    pv.y = f2bf(acc[mt][nt][1] + bz);
                    pv.z = f2bf(acc[mt][nt][2] + bz);
                    pv.w = f2bf(acc[mt][nt][3] + bz);
                    *(ushort4*)&Vt[d * TLD + rs * 64 + mt * 16 + q * 4] = pv;
                }
            }
        }
        if (tid == 0) {                            // head wait
            while (__hip_atomic_load(bar + 384 + h * 32, __ATOMIC_RELAXED,
                                     __HIP_MEMORY_SCOPE_AGENT) < 4u * s)
                __builtin_amdgcn_s_sleep(1);
        }
        __syncthreads();

        // ---------- gather the 3 peer slices into LDS ----------
        {
            if (wave != rs) {                      // K: thread -> key row tid
                const ushort_t* kr = Kx + tid * 64;
                uint4 kb4[8];
#pragma unroll
                for (int s8 = 0; s8 < 8; ++s8)
                    kb4[s8] = *(const uint4*)(kr + s8 * 8);
                const int kp = (tid >> 4) & 3;     // seg rotation (bank spread)
#pragma unroll
                for (int s8 = 0; s8 < 8; ++s8) {
                    int ks = (s8 + kp) & 7;
                    *(uint4*)&Kl[tid * KLD + ks * 8] = kb4[ks];
                }
            }
            const int vd = tid >> 2, vq = tid & 3;
            if (vq != rs) {                        // V: [dim][key-quarter]
                const ushort_t* vr = Vx + vd * 256 + vq * 64;
                uint4 vb4[8];
#pragma unroll
                for (int s8 = 0; s8 < 8; ++s8)
                    vb4[s8] = *(const uint4*)(vr + s8 * 8);
                const int vp = vq << 1;
#pragma unroll
                for (int s8 = 0; s8 < 8; ++s8) {
                    int vs = (s8 + vp) & 7;
                    *(uint4*)&Vt[vd * TLD + vq * 64 + vs * 8] = vb4[vs];
                }
            }
        }
        __syncthreads();

        // ---------- attention: wave w -> rows rs*64 + w*16 .. +16 ----------
        ushort_t* AOcur = AOb + (size_t)(i & 7) * WIN;
        {
            const int pl0 = wave * 16;              // local P row base
            floatx4 sc[16];
#pragma unroll
            for (int nt = 0; nt < 16; ++nt) sc[nt] = (floatx4){0.f, 0.f, 0.f, 0.f};
#pragma unroll
            for (int kc = 0; kc < 64; kc += 32) {
                short8 a = (kc == 0) ? qf0 : qf1;
#pragma unroll
                for (int nt = 0; nt < 16; ++nt) {
                    short8 b = *(const short8*)&Kl[(nt * 16 + fr) * KLD + kc + fk];
                    sc[nt] = __builtin_amdgcn_mfma_f32_16x16x32_bf16(
                        a, b, sc[nt], 0, 0, 0);
                }
            }
            float rmax[4] = {-INFINITY, -INFINITY, -INFINITY, -INFINITY};
#pragma unroll
            for (int nt = 0; nt < 16; ++nt)
#pragma unroll
                for (int rg = 0; rg < 4; ++rg) rmax[rg] = fmaxf(rmax[rg], sc[nt][rg]);
#pragma unroll
            for (int d = 1; d < 16; d <<= 1)
#pragma unroll
                for (int rg = 0; rg < 4; ++rg)
                    rmax[rg] = fmaxf(rmax[rg], __shfl_xor(rmax[rg], d));
            float rsum[4] = {0.f, 0.f, 0.f, 0.f};
#pragma unroll
            for (int nt = 0; nt < 16; ++nt) {
#pragma unroll
                for (int rg = 0; rg < 4; ++rg) {
                    float p = __expf((sc[nt][rg] - rmax[rg]) * 0.125f);
                    rsum[rg] += p;
                    P[(pl0 + q * 4 + rg) * TLD + nt * 16 + fr] = f2bf(p);
                }
            }
#pragma unroll
            for (int d = 1; d < 16; d <<= 1)
#pragma unroll
                for (int rg = 0; rg < 4; ++rg) rsum[rg] += __shfl_xor(rsum[rg], d);

            floatx4 o[4];
#pragma unroll
            for (int nt = 0; nt < 4; ++nt) o[nt] = (floatx4){0.f, 0.f, 0.f, 0.f};
#pragma unroll
            for (int kt = 0; kt < 8; ++kt) {
                short8 a = *(const short8*)&P[(pl0 + fr) * TLD + kt * 32 + fk];
#pragma unroll
                for (int nt = 0; nt < 4; ++nt) {
                    short8 b = *(const short8*)&Vt[(nt * 16 + fr) * TLD + kt * 32 + fk];
                    o[nt] = __builtin_amdgcn_mfma_f32_16x16x32_bf16(
                        a, b, o[nt], 0, 0, 0);
                }
            }
            float linv[4];
#pragma unroll
            for (int rg = 0; rg < 4; ++rg) linv[rg] = 1.f / rsum[rg];
#pragma unroll
            for (int nt = 0; nt < 4; ++nt)
#pragma unroll
                for (int rg = 0; rg < 4; ++rg) {
                    int row = m0g + q * 4 + rg;
                    st2_wt(AOcur + (size_t)row * 1024 + h * 64 + nt * 16 + fr,
                           f2bf(o[nt][rg] * linv[rg]));
                }
        }

        // ------ per-rs grid barrier: arrive / prefetch-next / wait ------
        // 16 WGs (all heads, same rs) share counter bar[960 + rs*16].
        rel_drain();
        __syncthreads();
        if (tid == 0)                              // arrive
            __hip_atomic_fetch_add(bar + 960 + rs * 16, 1u,
                    __ATOMIC_RELAXED, __HIP_MEMORY_SCOPE_AGENT);
        const bool more = (t0 + 1 < nsteps);
        if (more) {                                // barrier-independent work
            stage_W(Wc, h, 0,  sm.st.Wb[0], wave, lane);   // next i >= 2
            stage_W(Wc, h, 64, sm.st.Wb[0] + 8192, wave, lane);
            const ushort_t* Qrow = Qchunk + (size_t)(i + 1 - w0) * WIN
                + (size_t)(m0g + fr) * 1024 + h * 64;
            qf0 = *(const short8*)(Qrow);
            qf1 = *(const short8*)(Qrow + 32);
        }
        if (tid == 0 && more) {                    // wait (skipped on final step)
            while (__hip_atomic_load(bar + 960 + rs * 16, __ATOMIC_RELAXED,
                                     __HIP_MEMORY_SCOPE_AGENT) < 16u * s)
                __builtin_amdgcn_s_sleep(1);
        }
        __syncthreads();
        if (more) {                                // AO_i rows [rs*64,+64) visible
            const ushort_t* An = AOb + (size_t)(i & 7) * WIN
                + (size_t)rs * 64 * 1024;
            stage_A(An, 0,  sm.st.Ab[0], wave, lane);
            stage_A(An, 64, sm.st.Ab[0] + 4096, wave, lane);
        }
    }
}

// ===========================================================================
// Fused cooperative kernel: grid 256 WGs x 256 thr, 1 WG/CU.
// XCD role partition (x = wg&7 assumed = XCD id; perf-only assumption):
//   x in {0,1}: scan WGs; h = (x<<3)|(y>>2); rs = y&3 (4 rs of a head
//               co-located on one XCD -> exchange stays in that L2).
//   x in {2..7}: 192 helpers computing phase-1 for chunk c+1.
// ===========================================================================
struct GemmSmem { ushort_t As[128 * 32]; ushort_t Bs[128 * 32]; };
union FusedSmem { ScanSmem scan; GemmSmem gem; AttnShared att; };

__global__ __launch_bounds__(256, 1) void fused_k(
    const ushort_t* __restrict__ Qchunk, int i0, int w0, int nsteps,
    const ushort_t* __restrict__ x0, ushort_t* __restrict__ AOb,
    ushort_t* __restrict__ KVx,
    const ushort_t* __restrict__ Wkv, const float* __restrict__ bkv,
    const ushort_t* __restrict__ Wc, const float* __restrict__ bc,
    unsigned* __restrict__ bar, unsigned s0,
    int do_help, int w0n,
    const ushort_t* __restrict__ path_bf,
    const ushort_t* __restrict__ w_in1, const float* __restrict__ b_in1,
    ushort_t* __restrict__ qkv, ushort_t* __restrict__ ao,
    ushort_t* __restrict__ ybuf,
    const ushort_t* __restrict__ w_out1, const float* __restrict__ b_out1,
    const ushort_t* __restrict__ w_lin, const float* __restrict__ b_lin,
    ushort_t* __restrict__ Xc,
    const ushort_t* __restrict__ w_in2, const float* __restrict__ b_in2,
    ushort_t* __restrict__ Qnext, unsigned hs0)
{
    __shared__ FusedSmem sm;
    const int wg = blockIdx.x;
    const int x = wg & 7, y = wg >> 3;

    if (x < 2) {
        const int h  = (x << 3) | (y >> 2);
        const int rs = y & 3;
        scan_body(sm.scan, h, rs,
                  Qchunk, i0, w0, nsteps, x0, AOb, KVx,
                  Wkv, bkv, Wc, bc, bar, s0);
        return;
    }
    if (!do_help) return;

    const int hw = (x - 2) * 32 + y; // 0..191
    const int hg = hw >> 3;          // 24 groups of 8

    // stage 1: qkv = gather(path) @ w_in1^T + b_in1  (384 tiles, 2 per WG)
    for (int t = hw; t < 384; t += 192) {
        int bx = t % 24, by = t / 24;
        gemm_core<true, true>(sm.gem.As, sm.gem.Bs, path_bf, 1024, w0n,
                              w_in1, b_in1, qkv, nullptr, 3072, 1024,
                              by * 128, bx * 128, bx * 128, 0);
    }
    help_bar(bar, hg, hs0);

    // stage 2: sliding attention (512 blocks)
    for (int t = hw; t < 512; t += 192) {
        int rs = t & 3, h = (t >> 2) & 15, b = t >> 6;
        attn_body(sm.att, qkv, ao, rs, h, b);
    }
    help_bar(bar, hg, hs0 + 1);

    // stage 3: y = ao @ w_out1^T + b_out1 (128 tiles)
    for (int t = hw; t < 128; t += 192) {
        int bx = t & 7, by = t >> 3;
        gemm_core<false, true>(sm.gem.As, sm.gem.Bs, ao, 1024, 0,
                               w_out1, b_out1, ybuf, nullptr, 1024, 1024,
                               by * 128, bx * 128, bx * 128, 0);
    }
    help_bar(bar, hg, hs0 + 2);

    // stage 4: X = relu(y @ w_lin^T + b_lin)
    for (int t = hw; t < 128; t += 192) {
        int bx = t & 7, by = t >> 3;
        gemm_core<false, true>(sm.gem.As, sm.gem.Bs, ybuf, 1024, 0,
                               w_lin, b_lin, Xc, nullptr, 1024, 1024,
                               by * 128, bx * 128, bx * 128, 1);
    }
    help_bar(bar, hg, hs0 + 3);

    // stage 5: Qnext = X @ wq^T + bq (rows 0..1023 of w_in2); consumed by
    // the NEXT launch's scan (kernel boundary provides release/acquire).
    for (int t = hw; t < 128; t += 192) {
        int bx = t & 7, by = t >> 3;
        gemm_core<false, true>(sm.gem.As, sm.gem.Bs, Xc, 1024, 0,
                               w_in2, b_in2, Qnext, nullptr, 1024, 1024,
                               by * 128, bx * 128, bx * 128, 0);
    }
}

// ---------------------------------------------------------------------------
extern "C" void kernel_launch(void* const* d_in, const int* in_sizes, int n_in,
                              void* d_out, int out_size, void* d_ws, size_t ws_size,
                              hipStream_t stream)
{
    const float* path   = (const float*)d_in[0];
    const float* w_in1  = (const float*)d_in[1];
    const float* b_in1  = (const float*)d_in[2];
    const float* w_out1 = (const float*)d_in[3];
    const float* b_out1 = (const float*)d_in[4];
    const float* w_lin  = (const float*)d_in[5];
    const float* b_lin  = (const float*)d_in[6];
    const float* w_in2  = (const float*)d_in[7];
    const float* b_in2  = (const float*)d_in[8];
    const float* w_out2 = (const float*)d_in[9];
    const float* b_out2 = (const float*)d_in[10];
    float* out = (float*)d_out;

    // workspace: barriers/bias (32 KB) then bf16 buffers (~78 MB)
    unsigned* bar = (unsigned*)d_ws;                      // 8 KB
    float* bc      = (float*)d_ws + 2048;                 // 2048 fp32
    float* zerosf  = bc + 2048;                           // 1024 fp32
    ushort_t* ws = (ushort_t*)d_ws + 16384;
    ushort_t* path_bf  = ws;                              // 4096*1024
    ushort_t* w_in1_bf = path_bf  + (size_t)4096 * 1024;  // 3072*1024
    ushort_t* w_out1_bf= w_in1_bf + (size_t)3072 * 1024;
    ushort_t* w_lin_bf = w_out1_bf+ (size_t)1024 * 1024;
    ushort_t* w_in2_bf = w_lin_bf + (size_t)1024 * 1024;  // 3072*1024
    ushort_t* w_out2_bf= w_in2_bf + (size_t)3072 * 1024;
    ushort_t* WoT_bf   = w_out2_bf+ (size_t)1024 * 1024;  // 1024*1024
    ushort_t* Wc_bf    = WoT_bf   + (size_t)1024 * 1024;  // 2048*1024
    ushort_t* qkv_bf   = Wc_bf    + (size_t)2048 * 1024;  // 2048*3072
    ushort_t* ao_bf    = qkv_bf   + (size_t)2048 * 3072;  // 2048*1024
    ushort_t* ybuf_bf  = ao_bf    + (size_t)2048 * 1024;  // 2048*1024
    ushort_t* Xbuf     = ybuf_bf  + (size_t)2048 * 1024;  // 2048*1024
    ushort_t* Qb0      = Xbuf     + (size_t)2048 * 1024;  // 2048*1024
    ushort_t* Qb1      = Qb0      + (size_t)2048 * 1024;  // 2048*1024
    ushort_t* AOb      = Qb1      + (size_t)2048 * 1024;  // 8 x 256*1024
    ushort_t* x0buf    = AOb + 8 * WIN;                   // 256*1024
    ushort_t* dummy    = x0buf + WIN;                     // 256*1024
    ushort_t* KVx      = dummy + WIN;                     // 8 x 16 x 32768 (8 MB)
    ushort_t* Qb[2] = {Qb0, Qb1};

    hipMemsetAsync(bar, 0, 8192, stream);
    hipMemsetAsync(zerosf, 0, 1024 * sizeof(float), stream);

    cast_bf_k<<<4096, 256, 0, stream>>>(path,  path_bf,  4096 * 1024);
    cast_bf_k<<<3072, 256, 0, stream>>>(w_in1, w_in1_bf, 3072 * 1024);
    cast_bf_k<<<1024, 256, 0, stream>>>(w_out1, w_out1_bf, 1024 * 1024);
    cast_bf_k<<<1024, 256, 0, stream>>>(w_lin, w_lin_bf, 1024 * 1024);
    cast_bf_k<<<3072, 256, 0, stream>>>(w_in2, w_in2_bf, 3072 * 1024);
    cast_bf_k<<<1024, 256, 0, stream>>>(w_out2, w_out2_bf, 1024 * 1024);

    // fused scan weights: Wc = Wkv @ Wo  (bf16), bc = bkv + Wkv @ bo (fp32)
    transpose_k<<<dim3(16, 16), 256, 0, stream>>>(w_out2_bf, WoT_bf);
    bc_k<<<8, 256, 0, stream>>>(w_in2, b_in2, b_out2, bc);
    gemm_bf_k<<<dim3(8, 16), 256, 0, stream>>>(
        w_in2_bf + (size_t)1024 * 1024, 1024, WoT_bf, zerosf,
        Wc_bf, nullptr, 1024, 1024, 0);

    // ---- Phase 1 for chunk 0 (separate kernels; later chunks are fused) ----
    gemm_qkv_k<<<dim3(24, 16), 256, 0, stream>>>(
        path_bf, w_in1_bf, b_in1, qkv_bf, 0);
    attn_mfma_k<<<dim3(4, NH, CHUNK), 256, 0, stream>>>(qkv_bf, ao_bf);
    gemm_bf_k<<<dim3(8, 16), 256, 0, stream>>>(
        ao_bf, 1024, w_out1_bf, b_out1, ybuf_bf, nullptr, 1024, 1024, 0);
    gemm_bf_k<<<dim3(8, 16), 256, 0, stream>>>(
        ybuf_bf, 1024, w_lin_bf, b_lin, Xbuf, nullptr, 1024, 1024, 1);
    gemm_bf_k<<<dim3(8, 16), 256, 0, stream>>>(
        Xbuf, 1024, w_in2_bf, b_in2, Qb[0], nullptr, 1024, 1024, 0);
    (void)hipMemcpyAsync(x0buf, Xbuf, WIN * sizeof(ushort_t),
                         hipMemcpyDeviceToDevice, stream);

    unsigned sbase = 1;
    for (int c = 0; c < NCHUNK; ++c) {
        int w0 = c * CHUNK;
        int i0 = (c == 0) ? 1 : w0;
        int nsteps = (c == 0) ? CHUNK - 1 : CHUNK;
        int do_help = (c + 1 < NCHUNK) ? 1 : 0;
        int w0n = (c + 1) * CHUNK;
        unsigned hs0 = (unsigned)(c * 4 + 1);
        const ushort_t* Qcur = Qb[c & 1];
        ushort_t* Qnext = Qb[(c + 1) & 1];
        const ushort_t* x0P = x0buf;
        ushort_t* AObP = AOb;
        ushort_t* KVxP = KVx;
        const ushort_t* WkvP = w_in2_bf + (size_t)1024 * 1024;
        const float* bkvP = b_in2 + 1024;
        const ushort_t* WcP = Wc_bf;
        const float* bcP = bc;
        unsigned* barP = bar;
        unsigned sb = sbase;
        const ushort_t* pathP = path_bf;
        const ushort_t* win1P = w_in1_bf;
        const float* bin1P = b_in1;
        ushort_t* qkvP = qkv_bf;
        ushort_t* aoP = ao_bf;
        ushort_t* ybufP = ybuf_bf;
        const ushort_t* wout1P = w_out1_bf;
        const float* bout1P = b_out1;
        const ushort_t* wlinP = w_lin_bf;
        const float* blinP = b_lin;
        ushort_t* XP = Xbuf;
        const ushort_t* win2P = w_in2_bf;
        const float* bin2P = b_in2;
        void* args[] = {&Qcur, &i0, &w0, &nsteps, &x0P, &AObP, &KVxP,
                        &WkvP, &bkvP, &WcP, &bcP, &barP, &sb,
                        &do_help, &w0n, &pathP, &win1P, &bin1P,
                        &qkvP, &aoP, &ybufP, &wout1P, &bout1P,
                        &wlinP, &blinP, &XP, &win2P, &bin2P, &Qnext, &hs0};
        hipLaunchCooperativeKernel((void*)fused_k, dim3(256), dim3(256),
                                   args, 0, stream);
        sbase += (unsigned)nsteps;
    }

    // final out-projection: out = AO_239 @ Wo^T + bo  (fp32 to d_out)
    gemm_bf_k<<<dim3(8, 2), 256, 0, stream>>>(
        AOb + (size_t)((N_WIN - 1) & 7) * WIN, 1024, w_out2_bf, b_out2,
        dummy, out, 1024, 1024, 0);
}